// Round 9
// baseline (282.995 us; speedup 1.0000x reference)
//
#include <hip/hip_runtime.h>
#include <math.h>

#define NEG 0.2f
#define LDSW 520   // LDS row stride in shorts; row-bank-stride 4 spreads MLP A-reads
#define CAP 96     // bucket capacity per dst node (deg ~ binomial, mean 16, 20 sigma)

typedef short bf16x8 __attribute__((ext_vector_type(8)));
typedef float f32x4  __attribute__((ext_vector_type(4)));
typedef float f32x2  __attribute__((ext_vector_type(2)));

// ---------------------------------------------------------------------------
// helpers
// ---------------------------------------------------------------------------
static __device__ __forceinline__ f32x2 pkfma(f32x2 a, f32x2 b, f32x2 c) {
    return __builtin_elementwise_fma(a, b, c);   // -> v_pk_fma_f32
}
static __device__ __forceinline__ f32x2 splat2(float x) { return (f32x2){x, x}; }

static __device__ __forceinline__ unsigned short f2bf(float f) {   // RNE, finite
    unsigned int x = __float_as_uint(f);
    unsigned int r = (x + 0x7FFFu + ((x >> 16) & 1u)) >> 16;
    return (unsigned short)r;
}
static __device__ __forceinline__ float rlane(float v, int l) {
    return __int_as_float(__builtin_amdgcn_readlane(__float_as_int(v), l));
}

// Sum across each 16-lane DPP row (head h = lanes 16h..16h+15).
#define DPP_ADD(x, ctrl) \
    ((x) + __int_as_float(__builtin_amdgcn_update_dpp( \
        __float_as_int(x), __float_as_int(x), (ctrl), 0xF, 0xF, true)))
static __device__ __forceinline__ float rowsum16(float v) {
    v = DPP_ADD(v, 0xB1);   // quad_perm xor1
    v = DPP_ADD(v, 0x4E);   // quad_perm xor2
    v = DPP_ADD(v, 0x141);  // row_half_mirror
    v = DPP_ADD(v, 0x140);  // row_mirror
    return v;
}

// ---------------------------------------------------------------------------
// Bucketed CSR build (R21) -- ONE dispatch replaces hist+scan+scatter.
// GAT reduction is order-independent -> slot = atomicAdd arrival order into
// fixed-capacity buckets (CAP=96 >> max degree). Wt transpose rides along;
// R22: transpose indexing swapped so WRITES are coalesced (k fastest).
// ---------------------------------------------------------------------------
__global__ void k_hist_scatter(
    const int* __restrict__ src_s, const int* __restrict__ dst_s, int Es,
    const int* __restrict__ src_n, const int* __restrict__ dst_n, int En,
    int* __restrict__ deg_s, int* __restrict__ deg_n,
    int* __restrict__ csr_s, int* __restrict__ csr_n,
    const float* __restrict__ W, unsigned short* __restrict__ Wt)
{
    int i = blockIdx.x * 256 + threadIdx.x;
    if (i < Es) {
        int d = dst_s[i];
        int p = atomicAdd(&deg_s[d], 1);
        if (p < CAP) csr_s[d * CAP + p] = src_s[i];
    }
    int j = i - Es;
    if (j >= 0 && j < En) {
        int d = dst_n[j];
        int p = atomicAdd(&deg_n[d], 1);
        if (p < CAP) csr_n[d * CAP + p] = src_n[j];
    }
    if (i < 512 * 256) {                 // W[512][256] f32 -> Wt[256][512] bf16
        int k = i & 511, n = i >> 9;     // k fastest -> coalesced Wt writes
        Wt[(size_t)n * 512 + k] = f2bf(W[k * 256 + n]);
    }
}

// ---------------------------------------------------------------------------
// One GATv2 layer for one wave's 4 dst nodes (nodebase..nodebase+3);
// results -> LDS rows ldsrow..ldsrow+3 (bf16 x4/lane). Full chunks of 8
// edges run UNGUARDED; tail chunk uses the wave-uniform per-edge branch
// (R16: padded bodies cost +33%; body verified at ~50us-equiv VALU floor).
// ---------------------------------------------------------------------------
#define EDGE_BODY { \
    f32x2 x0 = splat2(rlane(r0, j * 8 + 0)); \
    f32x2 x1 = splat2(rlane(r0, j * 8 + 1)); \
    f32x2 x2 = splat2(rlane(r0, j * 8 + 2)); \
    f32x2 x3 = splat2(rlane(r0, j * 8 + 3)); \
    f32x2 x4 = splat2(rlane(r0, j * 8 + 4)); \
    f32x2 x5 = splat2(rlane(r0, j * 8 + 5)); \
    f32x2 x6 = splat2(rlane(r0, j * 8 + 6)); \
    f32x2 x7 = splat2(rlane(r0, j * 8 + 7)); \
    f32x2 fs01 = bs01, fs23 = bs23; \
    fs01 = pkfma(x0, ws01[0], fs01); fs23 = pkfma(x0, ws23[0], fs23); \
    fs01 = pkfma(x1, ws01[1], fs01); fs23 = pkfma(x1, ws23[1], fs23); \
    fs01 = pkfma(x2, ws01[2], fs01); fs23 = pkfma(x2, ws23[2], fs23); \
    fs01 = pkfma(x3, ws01[3], fs01); fs23 = pkfma(x3, ws23[3], fs23); \
    fs01 = pkfma(x4, ws01[4], fs01); fs23 = pkfma(x4, ws23[4], fs23); \
    fs01 = pkfma(x5, ws01[5], fs01); fs23 = pkfma(x5, ws23[5], fs23); \
    fs01 = pkfma(x6, ws01[6], fs01); fs23 = pkfma(x6, ws23[6], fs23); \
    fs01 = pkfma(x7, ws01[7], fs01); fs23 = pkfma(x7, ws23[7], fs23); \
    f32x2 t01 = fs01 + fd01r; \
    f32x2 t23 = fs23 + fd23r; \
    t01 = __builtin_elementwise_max(t01, NEG * t01); \
    t23 = __builtin_elementwise_max(t23, NEG * t23); \
    f32x2 scp = t01 * at01; \
    scp = pkfma(t23, at23, scp); \
    float sc = scp.x + scp.y; \
    sc = rowsum16(sc); \
    float p = __expf(sc);   /* no max shift: |sc| bounded, verified R6-R21 */ \
    l += p; \
    f32x2 pp = splat2(p); \
    a01 = pkfma(pp, fs01, a01); \
    a23 = pkfma(pp, fs23, a23); }

static __device__ __forceinline__ void gat_layer4(
    const float* __restrict__ x_src, const int* __restrict__ csr,
    const float* __restrict__ Ws, const float* __restrict__ bs,
    const float* __restrict__ Wd, const float* __restrict__ bd,
    const float* __restrict__ at,
    const float* __restrict__ Wr, const float* __restrict__ br,
    float xag, int lane, int nodebase, int ldsrow, int n_dst,
    const int* st, const int* dg,          // [4] wave-uniform
    const int* i1pre, const float* x0pre,  // [4] preloaded chunk1-idx / chunk0-rows
    unsigned short* __restrict__ xt, int col)
{
    const int d0 = lane * 4;
    const int gs = lane >> 3;   // edge slot 0..7 within chunk
    const int w8 = lane & 7;    // word within the 8-float src row

    // ---- fd/fr for the wave's 4 nodes in one pass over the 32 weight rows
    f32x2 fd01[4], fd23[4], fr01[4], fr23[4];
    {
        float4 bdv = *(const float4*)&bd[d0];
        float4 brv = *(const float4*)&br[d0];
#pragma unroll
        for (int j = 0; j < 4; ++j) {
            fd01[j] = (f32x2){bdv.x, bdv.y}; fd23[j] = (f32x2){bdv.z, bdv.w};
            fr01[j] = (f32x2){brv.x, brv.y}; fr23[j] = (f32x2){brv.z, brv.w};
        }
#pragma unroll
        for (int k = 0; k < 16; ++k) {
            float4 wd = *(const float4*)&Wd[k * 256 + d0];
            float4 wr = *(const float4*)&Wr[k * 256 + d0];
            f32x2 wd01 = {wd.x, wd.y}, wd23 = {wd.z, wd.w};
            f32x2 wr01 = {wr.x, wr.y}, wr23 = {wr.z, wr.w};
#pragma unroll
            for (int j = 0; j < 4; ++j) {
                f32x2 xk = splat2(rlane(xag, j * 16 + k));
                fd01[j] = pkfma(xk, wd01, fd01[j]);
                fd23[j] = pkfma(xk, wd23, fd23[j]);
                fr01[j] = pkfma(xk, wr01, fr01[j]);
                fr23[j] = pkfma(xk, wr23, fr23[j]);
            }
        }
    }

    // ---- edge-loop constants (packed pairs)
    f32x2 ws01[8], ws23[8];
#pragma unroll
    for (int k = 0; k < 8; ++k) {
        float4 w = *(const float4*)&Ws[k * 256 + d0];
        ws01[k] = (f32x2){w.x, w.y};
        ws23[k] = (f32x2){w.z, w.w};
    }
    f32x2 bs01, bs23, at01, at23;
    {
        float4 b4 = *(const float4*)&bs[d0];
        float4 a4 = *(const float4*)&at[d0];
        bs01 = (f32x2){b4.x, b4.y}; bs23 = (f32x2){b4.z, b4.w};
        at01 = (f32x2){a4.x, a4.y}; at23 = (f32x2){a4.z, a4.w};
    }

#pragma unroll
    for (int rep = 0; rep < 4; ++rep) {
        const int node = nodebase + rep;
        if (node >= n_dst) continue;

        const int start = st[rep];
        const int deg   = dg[rep];
        const f32x2 fd01r = fd01[rep], fd23r = fd23[rep];

        float l = 0.f;
        f32x2 a01 = {0.f, 0.f}, a23 = {0.f, 0.f};

        if (deg > 0) {
            float r0 = x0pre[rep];         // chunk-0 rows already resident
            int   i1 = i1pre[rep];         // chunk-1 indices already resident
            const int nfull = deg >> 3, tail = deg & 7;

            for (int c = 0; c < nfull; ++c) {
                float r1 = x_src[(size_t)i1 * 8 + w8];
                int e2 = c * 8 + 16 + gs; e2 = (e2 < deg) ? e2 : deg - 1;
                int i2 = csr[start + e2];
#pragma unroll
                for (int j = 0; j < 8; ++j) EDGE_BODY   // unguarded full chunk
                r0 = r1; i1 = i2;
            }
            if (tail) {
#pragma unroll
                for (int j = 0; j < 8; ++j)
                    if (j < tail) EDGE_BODY              // uniform scalar branch
            }
        }

        float inv = (l > 0.f) ? 1.f / l : 0.f;   // zero in-degree -> rst = 0
        ushort4 o;
        o.x = f2bf(fmaxf(fmaf(a01.x, inv, fr01[rep].x), 0.f));
        o.y = f2bf(fmaxf(fmaf(a01.y, inv, fr01[rep].y), 0.f));
        o.z = f2bf(fmaxf(fmaf(a23.x, inv, fr23[rep].x), 0.f));
        o.w = f2bf(fmaxf(fmaf(a23.y, inv, fr23[rep].y), 0.f));
        *(ushort4*)(&xt[(ldsrow + rep) * LDSW + col + lane * 4]) = o;
    }
}

// ---------------------------------------------------------------------------
// Fused GAT(seen)||GAT(near) + MLP. R22: block = 256 thr (4 waves), 8 nodes.
// Waves 0-1: seen layer (4 nodes each); waves 2-3: near layer (same nodes).
// Each wave = R13's proven unit. Rationale vs R20/21's 512-thr blocks
// (138us, occupancy 21% ~= 1 block/CU avg): 256-thr blocks fit 4/CU
// (2x TLP to hide barrier idle + gather latency), 2500 blocks = 9.8 CU
// fills (smooth packing, short drain tail), barrier spans 4 waves not 8.
// MLP: 8-row x 256-col tile, proven k_mlp shape, A-frag rows 8-15 = pad
// (MFMA ~free at 1.5% util; pad stores guarded off).
// ---------------------------------------------------------------------------
__global__ __launch_bounds__(256) void k_gatmlp(
    const float* __restrict__ xsrc_s, const int* __restrict__ deg_s_a, const int* __restrict__ csr_s,
    const float* __restrict__ Ws_s, const float* __restrict__ bs_s,
    const float* __restrict__ Wd_s, const float* __restrict__ bd_s,
    const float* __restrict__ at_s,
    const float* __restrict__ Wr_s, const float* __restrict__ br_s,
    const float* __restrict__ xsrc_n, const int* __restrict__ deg_n_a, const int* __restrict__ csr_n,
    const float* __restrict__ Ws_n, const float* __restrict__ bs_n,
    const float* __restrict__ Wd_n, const float* __restrict__ bd_n,
    const float* __restrict__ at_n,
    const float* __restrict__ Wr_n, const float* __restrict__ br_n,
    const float* __restrict__ x_ag,
    const unsigned short* __restrict__ Wt, const float* __restrict__ bmlp,
    float* __restrict__ out, int n_dst)
{
    __shared__ unsigned short xt[16 * LDSW];   // 16 rows (8 data + 8 MFMA pad)

    const int t = threadIdx.x;
    const int wave = t >> 6, lane = t & 63;
    const bool seen = wave < 2;
    const int w2 = wave & 1;                   // which node-quad of the block
    const int gs = lane >> 3, w8 = lane & 7;
    const int nb = (int)blockIdx.x * 8;
    const int nodebase = nb + w2 * 4;
    const int ldsrow = w2 * 4;

    // ---- per-wave layer bindings (wave-uniform -> SGPR cselect)
    const float* x_src = seen ? xsrc_s : xsrc_n;
    const int*   degp  = seen ? deg_s_a : deg_n_a;
    const int*   csr   = seen ? csr_s  : csr_n;
    const float* Ws    = seen ? Ws_s   : Ws_n;
    const float* bs    = seen ? bs_s   : bs_n;
    const float* Wd    = seen ? Wd_s   : Wd_n;
    const float* bd    = seen ? bd_s   : bd_n;
    const float* at    = seen ? at_s   : at_n;
    const float* Wr    = seen ? Wr_s   : Wr_n;
    const float* br    = seen ? br_s   : br_n;
    const int col = seen ? 0 : 256;

    // ---- gather the wave's 4 agent rows: lane L = feat (L&15) of node
    //      nodebase + (L>>4)
    int gnode = nodebase + (lane >> 4);
    int gn = (gnode < n_dst) ? gnode : (n_dst - 1);
    float xag = x_ag[(size_t)gn * 16 + (lane & 15)];

    // ---- edge ranges for the wave's 4 nodes (bucketed: one deg load each)
    int st[4], dg[4];
#pragma unroll
    for (int j = 0; j < 4; ++j) {
        int nd = nodebase + j;
        nd = (nd < n_dst) ? nd : (n_dst - 1);
        int d = degp[nd];
        dg[j] = (d < CAP) ? d : CAP;
        st[j] = nd * CAP;
    }

    // ---- hoist chunk0/chunk1 csr indices + chunk0 x rows (in flight under
    //      the fd/fr weight pass inside gat_layer4)
    int i0[4], i1[4];
#pragma unroll
    for (int j = 0; j < 4; ++j) {
        int dgj = dg[j];
        if (dgj > 0) {
            int e0 = (gs < dgj) ? gs : dgj - 1;
            int e1 = (8 + gs < dgj) ? 8 + gs : dgj - 1;
            i0[j] = csr[st[j] + e0];
            i1[j] = csr[st[j] + e1];
        } else { i0[j] = 0; i1[j] = 0; }
    }
    float x0[4];
#pragma unroll
    for (int j = 0; j < 4; ++j)
        x0[j] = x_src[(size_t)i0[j] * 8 + w8];

    gat_layer4(x_src, csr, Ws, bs, Wd, bd, at, Wr, br,
               xag, lane, nodebase, ldsrow, n_dst, st, dg, i1, x0, xt, col);

    __syncthreads();

    // ---- MLP: out[8,256] = relu(xt[0:8] @ Wt^T + b); wave w: cols 64w..64w+63.
    //      A-frag rows 8-15 are pad (garbage LDS) -> those stores guarded off.
    const int m16 = lane & 15, q = lane >> 4;
    const int nbase = wave * 64;
    const unsigned short* w0 = Wt + (size_t)(nbase + m16) * 512 + q * 8;
    const unsigned short* w1 = w0 + 16 * 512;
    const unsigned short* w2p = w0 + 32 * 512;
    const unsigned short* w3 = w0 + 48 * 512;
    const unsigned short* ap = &xt[m16 * LDSW + q * 8];

    f32x4 ac0 = {0.f, 0.f, 0.f, 0.f}, ac1 = ac0, ac2 = ac0, ac3 = ac0;
#pragma unroll
    for (int k0 = 0; k0 < 512; k0 += 32) {
        bf16x8 a  = *(const bf16x8*)(ap + k0);
        bf16x8 b0 = *(const bf16x8*)(w0 + k0);
        bf16x8 b1 = *(const bf16x8*)(w1 + k0);
        bf16x8 b2 = *(const bf16x8*)(w2p + k0);
        bf16x8 b3 = *(const bf16x8*)(w3 + k0);
        ac0 = __builtin_amdgcn_mfma_f32_16x16x32_bf16(a, b0, ac0, 0, 0, 0);
        ac1 = __builtin_amdgcn_mfma_f32_16x16x32_bf16(a, b1, ac1, 0, 0, 0);
        ac2 = __builtin_amdgcn_mfma_f32_16x16x32_bf16(a, b2, ac2, 0, 0, 0);
        ac3 = __builtin_amdgcn_mfma_f32_16x16x32_bf16(a, b3, ac3, 0, 0, 0);
    }

#define EPI(AC, J) { \
        int coln = nbase + (J) * 16 + m16; \
        float bv = bmlp[coln]; \
        _Pragma("unroll") \
        for (int r = 0; r < 4; ++r) { \
            int lrow = q * 4 + r; \
            int orow = nb + lrow; \
            if (lrow < 8 && orow < n_dst) \
                out[(size_t)orow * 256 + coln] = fmaxf(AC[r] + bv, 0.f); \
        } }
    EPI(ac0, 0) EPI(ac1, 1) EPI(ac2, 2) EPI(ac3, 3)
#undef EPI
}

// ---------------------------------------------------------------------------
extern "C" void kernel_launch(void* const* d_in, const int* in_sizes, int n_in,
                              void* d_out, int out_size, void* d_ws, size_t ws_size,
                              hipStream_t stream) {
    const float* x_gt   = (const float*)d_in[0];
    const float* x_ubs  = (const float*)d_in[1];
    const float* x_ag   = (const float*)d_in[2];
    const int* seen_src = (const int*)d_in[3];
    const int* seen_dst = (const int*)d_in[4];
    const int* near_src = (const int*)d_in[5];
    const int* near_dst = (const int*)d_in[6];
    const float* Ws_s = (const float*)d_in[7];  const float* bs_s = (const float*)d_in[8];
    const float* Wd_s = (const float*)d_in[9];  const float* bd_s = (const float*)d_in[10];
    const float* at_s = (const float*)d_in[11];
    const float* Wr_s = (const float*)d_in[12]; const float* br_s = (const float*)d_in[13];
    const float* Ws_n = (const float*)d_in[14]; const float* bs_n = (const float*)d_in[15];
    const float* Wd_n = (const float*)d_in[16]; const float* bd_n = (const float*)d_in[17];
    const float* at_n = (const float*)d_in[18];
    const float* Wr_n = (const float*)d_in[19]; const float* br_n = (const float*)d_in[20];
    const float* W_a  = (const float*)d_in[21]; const float* b_a  = (const float*)d_in[22];

    const int n_ag = in_sizes[2] / 16;
    const int E_s  = in_sizes[3];
    const int E_n  = in_sizes[5];

    char* ws = (char*)d_ws;
    int* deg_s = (int*)ws;              ws += (size_t)n_ag * 4;
    int* deg_n = (int*)ws;              ws += (size_t)n_ag * 4;
    int* csr_s = (int*)ws;              ws += (size_t)n_ag * CAP * 4;
    int* csr_n = (int*)ws;              ws += (size_t)n_ag * CAP * 4;
    unsigned short* Wt = (unsigned short*)ws;  // [256][512] bf16

    hipMemsetAsync(deg_s, 0, (size_t)n_ag * 8, stream);  // deg_s, deg_n contiguous

    int gE = (E_s + E_n + 255) / 256;    // >= 512, also covers Wt transpose
    k_hist_scatter<<<gE, 256, 0, stream>>>(
        seen_src, seen_dst, E_s, near_src, near_dst, E_n,
        deg_s, deg_n, csr_s, csr_n, W_a, Wt);

    int gN = (n_ag + 7) / 8;   // 8 nodes per block (4 waves: 2 seen + 2 near)
    k_gatmlp<<<gN, 256, 0, stream>>>(
        x_gt,  deg_s, csr_s, Ws_s, bs_s, Wd_s, bd_s, at_s, Wr_s, br_s,
        x_ubs, deg_n, csr_n, Ws_n, bs_n, Wd_n, bd_n, at_n, Wr_n, br_n,
        x_ag, Wt, b_a, (float*)d_out, n_ag);
}

// Round 10
// 255.854 us; speedup vs baseline: 1.1061x; 1.1061x over previous
//
#include <hip/hip_runtime.h>
#include <math.h>

#define NEG 0.2f
#define LDSW 520   // LDS row stride in shorts; row-bank-stride 4 spreads MLP A-reads
#define CAP 48     // bucket capacity per dst node (deg ~ Poisson(16); P(>=48) ~ 1e-11)

typedef short bf16x8 __attribute__((ext_vector_type(8)));
typedef float f32x4  __attribute__((ext_vector_type(4)));
typedef float f32x2  __attribute__((ext_vector_type(2)));

// ---------------------------------------------------------------------------
// helpers
// ---------------------------------------------------------------------------
static __device__ __forceinline__ f32x2 pkfma(f32x2 a, f32x2 b, f32x2 c) {
    return __builtin_elementwise_fma(a, b, c);   // -> v_pk_fma_f32
}
static __device__ __forceinline__ f32x2 splat2(float x) { return (f32x2){x, x}; }

static __device__ __forceinline__ unsigned short f2bf(float f) {   // RNE, finite
    unsigned int x = __float_as_uint(f);
    unsigned int r = (x + 0x7FFFu + ((x >> 16) & 1u)) >> 16;
    return (unsigned short)r;
}
static __device__ __forceinline__ float rlane(float v, int l) {
    return __int_as_float(__builtin_amdgcn_readlane(__float_as_int(v), l));
}

// Sum across each 16-lane DPP row (head h = lanes 16h..16h+15).
#define DPP_ADD(x, ctrl) \
    ((x) + __int_as_float(__builtin_amdgcn_update_dpp( \
        __float_as_int(x), __float_as_int(x), (ctrl), 0xF, 0xF, true)))
static __device__ __forceinline__ float rowsum16(float v) {
    v = DPP_ADD(v, 0xB1);   // quad_perm xor1
    v = DPP_ADD(v, 0x4E);   // quad_perm xor2
    v = DPP_ADD(v, 0x141);  // row_half_mirror
    v = DPP_ADD(v, 0x140);  // row_mirror
    return v;
}

// ---------------------------------------------------------------------------
// Bucketed CSR build (R21) -- ONE dispatch replaces hist+scan+scatter.
// GAT reduction is order-independent -> slot = atomicAdd arrival order into
// fixed-capacity buckets. R23: CAP 96->48 halves the csr footprint (7.7MB
// both layers) -> denser scattered writes here, denser gathers in gatmlp.
// Wt transpose (W[512][256] f32 -> Wt[256][512] bf16) rides along.
// ---------------------------------------------------------------------------
__global__ void k_hist_scatter(
    const int* __restrict__ src_s, const int* __restrict__ dst_s, int Es,
    const int* __restrict__ src_n, const int* __restrict__ dst_n, int En,
    int* __restrict__ deg_s, int* __restrict__ deg_n,
    int* __restrict__ csr_s, int* __restrict__ csr_n,
    const float* __restrict__ W, unsigned short* __restrict__ Wt)
{
    int i = blockIdx.x * 256 + threadIdx.x;
    if (i < Es) {
        int d = dst_s[i];
        int p = atomicAdd(&deg_s[d], 1);
        if (p < CAP) csr_s[d * CAP + p] = src_s[i];
    }
    int j = i - Es;
    if (j >= 0 && j < En) {
        int d = dst_n[j];
        int p = atomicAdd(&deg_n[d], 1);
        if (p < CAP) csr_n[d * CAP + p] = src_n[j];
    }
    if (i < 512 * 256) {                 // W[512][256] f32 -> Wt[256][512] bf16
        int k = i >> 8, n = i & 255;     // coalesced reads of W
        Wt[(size_t)n * 512 + k] = f2bf(W[i]);
    }
}

// ---------------------------------------------------------------------------
// One GATv2 layer for one wave's 4 dst nodes; results -> LDS (bf16 x4/lane).
// Full chunks of 8 edges run UNGUARDED; tail chunk uses the wave-uniform
// per-edge branch (R16: padded bodies cost +33%; body verified at the
// ~50us-equiv VALU floor, R13/R18/R20/R21).
// ---------------------------------------------------------------------------
#define EDGE_BODY { \
    f32x2 x0 = splat2(rlane(r0, j * 8 + 0)); \
    f32x2 x1 = splat2(rlane(r0, j * 8 + 1)); \
    f32x2 x2 = splat2(rlane(r0, j * 8 + 2)); \
    f32x2 x3 = splat2(rlane(r0, j * 8 + 3)); \
    f32x2 x4 = splat2(rlane(r0, j * 8 + 4)); \
    f32x2 x5 = splat2(rlane(r0, j * 8 + 5)); \
    f32x2 x6 = splat2(rlane(r0, j * 8 + 6)); \
    f32x2 x7 = splat2(rlane(r0, j * 8 + 7)); \
    f32x2 fs01 = bs01, fs23 = bs23; \
    fs01 = pkfma(x0, ws01[0], fs01); fs23 = pkfma(x0, ws23[0], fs23); \
    fs01 = pkfma(x1, ws01[1], fs01); fs23 = pkfma(x1, ws23[1], fs23); \
    fs01 = pkfma(x2, ws01[2], fs01); fs23 = pkfma(x2, ws23[2], fs23); \
    fs01 = pkfma(x3, ws01[3], fs01); fs23 = pkfma(x3, ws23[3], fs23); \
    fs01 = pkfma(x4, ws01[4], fs01); fs23 = pkfma(x4, ws23[4], fs23); \
    fs01 = pkfma(x5, ws01[5], fs01); fs23 = pkfma(x5, ws23[5], fs23); \
    fs01 = pkfma(x6, ws01[6], fs01); fs23 = pkfma(x6, ws23[6], fs23); \
    fs01 = pkfma(x7, ws01[7], fs01); fs23 = pkfma(x7, ws23[7], fs23); \
    f32x2 t01 = fs01 + fd01r; \
    f32x2 t23 = fs23 + fd23r; \
    t01 = __builtin_elementwise_max(t01, NEG * t01); \
    t23 = __builtin_elementwise_max(t23, NEG * t23); \
    f32x2 scp = t01 * at01; \
    scp = pkfma(t23, at23, scp); \
    float sc = scp.x + scp.y; \
    sc = rowsum16(sc); \
    float p = __expf(sc);   /* no max shift: |sc| bounded, verified R6-R22 */ \
    l += p; \
    f32x2 pp = splat2(p); \
    a01 = pkfma(pp, fs01, a01); \
    a23 = pkfma(pp, fs23, a23); }

static __device__ __forceinline__ void gat_layer4(
    const float* __restrict__ x_src, const int* __restrict__ csr,
    const float* __restrict__ Ws, const float* __restrict__ bs,
    const float* __restrict__ Wd, const float* __restrict__ bd,
    const float* __restrict__ at,
    const float* __restrict__ Wr, const float* __restrict__ br,
    float xag, int lane, int w4, int nb, int n_dst,
    const int* st, const int* dg,          // [4] wave-uniform
    const int* i1pre, const float* x0pre,  // [4] preloaded chunk1-idx / chunk0-rows
    unsigned short* __restrict__ ldsbase)  // xt + col + lane*4 (shorts)
{
    const int d0 = lane * 4;
    const int gs = lane >> 3;   // edge slot 0..7 within chunk
    const int w8 = lane & 7;    // word within the 8-float src row

    // ---- fd/fr for the wave's 4 nodes in one pass over the 32 weight rows
    f32x2 fd01[4], fd23[4], fr01[4], fr23[4];
    {
        float4 bdv = *(const float4*)&bd[d0];
        float4 brv = *(const float4*)&br[d0];
#pragma unroll
        for (int j = 0; j < 4; ++j) {
            fd01[j] = (f32x2){bdv.x, bdv.y}; fd23[j] = (f32x2){bdv.z, bdv.w};
            fr01[j] = (f32x2){brv.x, brv.y}; fr23[j] = (f32x2){brv.z, brv.w};
        }
#pragma unroll
        for (int k = 0; k < 16; ++k) {
            float4 wd = *(const float4*)&Wd[k * 256 + d0];
            float4 wr = *(const float4*)&Wr[k * 256 + d0];
            f32x2 wd01 = {wd.x, wd.y}, wd23 = {wd.z, wd.w};
            f32x2 wr01 = {wr.x, wr.y}, wr23 = {wr.z, wr.w};
#pragma unroll
            for (int j = 0; j < 4; ++j) {
                f32x2 xk = splat2(rlane(xag, j * 16 + k));
                fd01[j] = pkfma(xk, wd01, fd01[j]);
                fd23[j] = pkfma(xk, wd23, fd23[j]);
                fr01[j] = pkfma(xk, wr01, fr01[j]);
                fr23[j] = pkfma(xk, wr23, fr23[j]);
            }
        }
    }

    // ---- edge-loop constants (packed pairs)
    f32x2 ws01[8], ws23[8];
#pragma unroll
    for (int k = 0; k < 8; ++k) {
        float4 w = *(const float4*)&Ws[k * 256 + d0];
        ws01[k] = (f32x2){w.x, w.y};
        ws23[k] = (f32x2){w.z, w.w};
    }
    f32x2 bs01, bs23, at01, at23;
    {
        float4 b4 = *(const float4*)&bs[d0];
        float4 a4 = *(const float4*)&at[d0];
        bs01 = (f32x2){b4.x, b4.y}; bs23 = (f32x2){b4.z, b4.w};
        at01 = (f32x2){a4.x, a4.y}; at23 = (f32x2){a4.z, a4.w};
    }

#pragma unroll
    for (int rep = 0; rep < 4; ++rep) {
        const int node = nb + rep * 4 + w4;
        if (node >= n_dst) continue;

        const int start = st[rep];
        const int deg   = dg[rep];
        const f32x2 fd01r = fd01[rep], fd23r = fd23[rep];

        float l = 0.f;
        f32x2 a01 = {0.f, 0.f}, a23 = {0.f, 0.f};

        if (deg > 0) {
            float r0 = x0pre[rep];         // chunk-0 rows already resident
            int   i1 = i1pre[rep];         // chunk-1 indices already resident
            const int nfull = deg >> 3, tail = deg & 7;

            for (int c = 0; c < nfull; ++c) {
                float r1 = x_src[(size_t)i1 * 8 + w8];
                int e2 = c * 8 + 16 + gs; e2 = (e2 < deg) ? e2 : deg - 1;
                int i2 = csr[start + e2];
#pragma unroll
                for (int j = 0; j < 8; ++j) EDGE_BODY   // unguarded full chunk
                r0 = r1; i1 = i2;
            }
            if (tail) {
#pragma unroll
                for (int j = 0; j < 8; ++j)
                    if (j < tail) EDGE_BODY              // uniform scalar branch
            }
        }

        float inv = (l > 0.f) ? 1.f / l : 0.f;   // zero in-degree -> rst = 0
        ushort4 o;
        o.x = f2bf(fmaxf(fmaf(a01.x, inv, fr01[rep].x), 0.f));
        o.y = f2bf(fmaxf(fmaf(a01.y, inv, fr01[rep].y), 0.f));
        o.z = f2bf(fmaxf(fmaf(a23.x, inv, fr23[rep].x), 0.f));
        o.w = f2bf(fmaxf(fmaf(a23.y, inv, fr23[rep].y), 0.f));
        *(ushort4*)(ldsbase + (rep * 4 + w4) * LDSW) = o;
    }
}

// ---------------------------------------------------------------------------
// Fused GAT(seen)||GAT(near) + MLP, LAYER-PARALLEL (R21 shape -- the best
// measured config: 138.5us, total 256.3). Block = 512 thr (8 waves),
// 16 nodes/block. Waves 0-3: seen layer; waves 4-7: near layer; each wave
// = R13's proven unit (one layer x 4 nodes). Barrier; 8-wave MFMA MLP
// (32 cols/wave) reads A from LDS. R22's 256-thr variant regressed (+30us):
// Wt read is a PER-BLOCK fixed cost (256KB) and occupancy is drain-limited,
// not slot-limited -- do not shrink blocks.
// R23: seen waves run at s_setprio(1) through the edge phase (T5 role
// diversity: seen carries 2x the edges; near waves yield issue slots they
// would otherwise burn before idling at the barrier).
// ---------------------------------------------------------------------------
__global__ __launch_bounds__(512) void k_gatmlp(
    const float* __restrict__ xsrc_s, const int* __restrict__ deg_s_a, const int* __restrict__ csr_s,
    const float* __restrict__ Ws_s, const float* __restrict__ bs_s,
    const float* __restrict__ Wd_s, const float* __restrict__ bd_s,
    const float* __restrict__ at_s,
    const float* __restrict__ Wr_s, const float* __restrict__ br_s,
    const float* __restrict__ xsrc_n, const int* __restrict__ deg_n_a, const int* __restrict__ csr_n,
    const float* __restrict__ Ws_n, const float* __restrict__ bs_n,
    const float* __restrict__ Wd_n, const float* __restrict__ bd_n,
    const float* __restrict__ at_n,
    const float* __restrict__ Wr_n, const float* __restrict__ br_n,
    const float* __restrict__ x_ag,
    const unsigned short* __restrict__ Wt, const float* __restrict__ bmlp,
    float* __restrict__ out, int n_dst)
{
    __shared__ unsigned short xt[16 * LDSW];   // 16.6 KB

    const int t = threadIdx.x;
    const int wave = t >> 6, lane = t & 63;
    const int w4 = wave & 3;
    const bool seen = wave < 4;
    const int gs = lane >> 3, w8 = lane & 7;
    const int nb = (int)blockIdx.x * 16;

    // ---- per-wave layer bindings (wave-uniform -> SGPR cselect)
    const float* x_src = seen ? xsrc_s : xsrc_n;
    const int*   degp  = seen ? deg_s_a : deg_n_a;
    const int*   csr   = seen ? csr_s  : csr_n;
    const float* Ws    = seen ? Ws_s   : Ws_n;
    const float* bs    = seen ? bs_s   : bs_n;
    const float* Wd    = seen ? Wd_s   : Wd_n;
    const float* bd    = seen ? bd_s   : bd_n;
    const float* at    = seen ? at_s   : at_n;
    const float* Wr    = seen ? Wr_s   : Wr_n;
    const float* br    = seen ? br_s   : br_n;
    const int col = seen ? 0 : 256;

    // ---- gather the wave's 4 agent rows: lane L = feat (L&15) of node L>>4
    int gnode = nb + ((lane >> 4) << 2) + w4;
    int gn = (gnode < n_dst) ? gnode : (n_dst - 1);
    float xag = x_ag[(size_t)gn * 16 + (lane & 15)];

    // ---- edge ranges for the wave's 4 nodes (bucketed: one deg load each)
    int st[4], dg[4];
#pragma unroll
    for (int j = 0; j < 4; ++j) {
        int nd = nb + j * 4 + w4;
        nd = (nd < n_dst) ? nd : (n_dst - 1);
        int d = degp[nd];
        dg[j] = (d < CAP) ? d : CAP;
        st[j] = nd * CAP;
    }

    // ---- hoist chunk0/chunk1 csr indices + chunk0 x rows (in flight under
    //      the fd/fr weight pass inside gat_layer4)
    int i0[4], i1[4];
#pragma unroll
    for (int j = 0; j < 4; ++j) {
        int dgj = dg[j];
        if (dgj > 0) {
            int e0 = (gs < dgj) ? gs : dgj - 1;
            int e1 = (8 + gs < dgj) ? 8 + gs : dgj - 1;
            i0[j] = csr[st[j] + e0];
            i1[j] = csr[st[j] + e1];
        } else { i0[j] = 0; i1[j] = 0; }
    }
    float x0[4];
#pragma unroll
    for (int j = 0; j < 4; ++j)
        x0[j] = x_src[(size_t)i0[j] * 8 + w8];

    if (seen) __builtin_amdgcn_s_setprio(1);   // critical-path waves first
    gat_layer4(x_src, csr, Ws, bs, Wd, bd, at, Wr, br,
               xag, lane, w4, nb, n_dst, st, dg, i1, x0, &xt[col + lane * 4]);
    __builtin_amdgcn_s_setprio(0);

    __syncthreads();

    // ---- MLP: out[16,256] = relu(xt @ Wt^T + b); wave w covers 32 cols
    const int m16 = lane & 15, q = lane >> 4;
    const unsigned short* w0 = Wt + (size_t)(wave * 32 + m16) * 512 + q * 8;
    const unsigned short* w1 = w0 + 16 * 512;
    const unsigned short* ap = &xt[m16 * LDSW + q * 8];

    f32x4 ac0 = {0.f, 0.f, 0.f, 0.f}, ac1 = ac0;
#pragma unroll
    for (int k0 = 0; k0 < 512; k0 += 32) {
        bf16x8 a  = *(const bf16x8*)(ap + k0);
        bf16x8 b0 = *(const bf16x8*)(w0 + k0);
        bf16x8 b1 = *(const bf16x8*)(w1 + k0);
        ac0 = __builtin_amdgcn_mfma_f32_16x16x32_bf16(a, b0, ac0, 0, 0, 0);
        ac1 = __builtin_amdgcn_mfma_f32_16x16x32_bf16(a, b1, ac1, 0, 0, 0);
    }

#define EPI(AC, J) { \
        int coln = wave * 32 + (J) * 16 + m16; \
        float bv = bmlp[coln]; \
        _Pragma("unroll") \
        for (int r = 0; r < 4; ++r) { \
            int orow = nb + q * 4 + r; \
            if (orow < n_dst) \
                out[(size_t)orow * 256 + coln] = fmaxf(AC[r] + bv, 0.f); \
        } }
    EPI(ac0, 0) EPI(ac1, 1)
#undef EPI
}

// ---------------------------------------------------------------------------
extern "C" void kernel_launch(void* const* d_in, const int* in_sizes, int n_in,
                              void* d_out, int out_size, void* d_ws, size_t ws_size,
                              hipStream_t stream) {
    const float* x_gt   = (const float*)d_in[0];
    const float* x_ubs  = (const float*)d_in[1];
    const float* x_ag   = (const float*)d_in[2];
    const int* seen_src = (const int*)d_in[3];
    const int* seen_dst = (const int*)d_in[4];
    const int* near_src = (const int*)d_in[5];
    const int* near_dst = (const int*)d_in[6];
    const float* Ws_s = (const float*)d_in[7];  const float* bs_s = (const float*)d_in[8];
    const float* Wd_s = (const float*)d_in[9];  const float* bd_s = (const float*)d_in[10];
    const float* at_s = (const float*)d_in[11];
    const float* Wr_s = (const float*)d_in[12]; const float* br_s = (const float*)d_in[13];
    const float* Ws_n = (const float*)d_in[14]; const float* bs_n = (const float*)d_in[15];
    const float* Wd_n = (const float*)d_in[16]; const float* bd_n = (const float*)d_in[17];
    const float* at_n = (const float*)d_in[18];
    const float* Wr_n = (const float*)d_in[19]; const float* br_n = (const float*)d_in[20];
    const float* W_a  = (const float*)d_in[21]; const float* b_a  = (const float*)d_in[22];

    const int n_ag = in_sizes[2] / 16;
    const int E_s  = in_sizes[3];
    const int E_n  = in_sizes[5];

    char* ws = (char*)d_ws;
    int* deg_s = (int*)ws;              ws += (size_t)n_ag * 4;
    int* deg_n = (int*)ws;              ws += (size_t)n_ag * 4;
    int* csr_s = (int*)ws;              ws += (size_t)n_ag * CAP * 4;
    int* csr_n = (int*)ws;              ws += (size_t)n_ag * CAP * 4;
    unsigned short* Wt = (unsigned short*)ws;  // [256][512] bf16

    hipMemsetAsync(deg_s, 0, (size_t)n_ag * 8, stream);  // deg_s, deg_n contiguous

    int gE = (E_s + E_n + 255) / 256;    // >= 512, also covers Wt transpose
    k_hist_scatter<<<gE, 256, 0, stream>>>(
        seen_src, seen_dst, E_s, near_src, near_dst, E_n,
        deg_s, deg_n, csr_s, csr_n, W_a, Wt);

    int gN = (n_ag + 15) / 16;   // 16 nodes per block (8 waves: 4 seen + 4 near)
    k_gatmlp<<<gN, 512, 0, stream>>>(
        x_gt,  deg_s, csr_s, Ws_s, bs_s, Wd_s, bd_s, at_s, Wr_s, br_s,
        x_ubs, deg_n, csr_n, Ws_n, bs_n, Wd_n, bd_n, at_n, Wr_n, br_n,
        x_ag, Wt, b_a, (float*)d_out, n_ag);
}